// Round 11
// baseline (297.061 us; speedup 1.0000x reference)
//
#include <hip/hip_runtime.h>
#include <hip/hip_fp16.h>
#include <math.h>

#define NBMAX 400   // max dst buckets (dst>>8), N=100k -> 391
#define GBUILD 2048 // build grid (k_scanA assumes GBUILD = 8*256)
#define GCAP 5120   // k_group LDS cache capacity (edges per bucket)

typedef __attribute__((ext_vector_type(8))) ushort us8;

__device__ inline ushort f2bf(float f) {
    unsigned u = __float_as_uint(f);
    u += 0x7fff + ((u >> 16) & 1);   // RNE
    return (ushort)(u >> 16);
}
__device__ inline float bf2f(ushort u) {
    return __uint_as_float(((unsigned)u) << 16);
}

// ----------------------------------------------------------- fp32 -> bf16
__global__ __launch_bounds__(256) void k_tobf16(const float4* __restrict__ X4,
                                                ushort4* __restrict__ Y4, int n4) {
    int i = blockIdx.x * 256 + threadIdx.x;
    if (i >= n4) return;
    float4 v = X4[i];
    ushort4 o;
    o.x = f2bf(v.x); o.y = f2bf(v.y); o.z = f2bf(v.z); o.w = f2bf(v.w);
    Y4[i] = o;
}

// ------------- build pass 0: per-block bucket histogram -> bh[blk][bucket]
__global__ __launch_bounds__(256) void k_hist(const int* __restrict__ dstv,
                                              int* __restrict__ bh,
                                              int E, int chunk) {
    __shared__ int lh[NBMAX];
    int tid = threadIdx.x;
    for (int i = tid; i < NBMAX; i += 256) lh[i] = 0;
    __syncthreads();
    int start = blockIdx.x * chunk;
    int end = min(E, start + chunk);
    for (int e = start + tid; e < end; e += 256)
        atomicAdd(&lh[dstv[e] >> 8], 1);
    __syncthreads();
    int* row = bh + (size_t)blockIdx.x * NBMAX;
    for (int i = tid; i < NBMAX; i += 256) row[i] = lh[i];
}

// ------------- build pass 1a: per-bucket scan over GBUILD blocks (8/thread)
__global__ __launch_bounds__(256) void k_scanA(const int* __restrict__ bh,
                                               int* __restrict__ boff,
                                               int* __restrict__ btot) {
    __shared__ int s[256];
    int b = blockIdx.x;     // bucket
    int t = threadIdx.x;
    int v[8];
    int sum = 0;
#pragma unroll
    for (int j = 0; j < 8; ++j) {
        v[j] = bh[(size_t)(t * 8 + j) * NBMAX + b];
        sum += v[j];
    }
    s[t] = sum;
    __syncthreads();
    for (int o = 1; o < 256; o <<= 1) {
        int tv = (t >= o) ? s[t - o] : 0;
        __syncthreads();
        s[t] += tv;
        __syncthreads();
    }
    int excl = s[t] - sum;
#pragma unroll
    for (int j = 0; j < 8; ++j) {
        boff[(size_t)(t * 8 + j) * NBMAX + b] = excl;
        excl += v[j];
    }
    if (t == 255) btot[b] = s[255];
}

// ------------- build pass 1b: scan bucket totals -> bbase (1 block)
__global__ __launch_bounds__(512) void k_scanB(const int* __restrict__ btot,
                                               int* __restrict__ bbase, int nb) {
    __shared__ int s[512];
    int t = threadIdx.x;
    int c = (t < nb) ? btot[t] : 0;
    s[t] = c;
    __syncthreads();
    for (int o = 1; o < 512; o <<= 1) {
        int v = (t >= o) ? s[t - o] : 0;
        __syncthreads();
        s[t] += v;
        __syncthreads();
    }
    if (t < nb) bbase[t] = s[t] - c;
}

// ------- build pass 2: SINGLE-PASS edge MLP + packed 8B bucket scatter
// spk[p] = { src, (dst&255)<<16 | fp16(w) }
__global__ __launch_bounds__(256) void k_edge_scatter(const float* __restrict__ ea,
                                                      const float* __restrict__ Wd1,
                                                      const float* __restrict__ bd1,
                                                      const float* __restrict__ Wd2,
                                                      const float* __restrict__ bd2,
                                                      const int* __restrict__ srcv,
                                                      const int* __restrict__ dstv,
                                                      const int* __restrict__ bbase,
                                                      const int* __restrict__ boff,
                                                      int2* __restrict__ spk,
                                                      int E, int chunk) {
    __shared__ float w1[16], b1[16], w2[16];
    __shared__ float b2s;
    __shared__ int gb[NBMAX], lc[NBMAX];
    int tid = threadIdx.x;
    if (tid < 16) {
        w1[tid] = Wd1[tid];
        b1[tid] = bd1[tid];
        w2[tid] = Wd2[tid];
    }
    if (tid == 0) b2s = bd2[0];
    const int* brow = boff + (size_t)blockIdx.x * NBMAX;
    for (int i = tid; i < NBMAX; i += 256) {
        gb[i] = bbase[i] + brow[i];
        lc[i] = 0;
    }
    __syncthreads();
    int start = blockIdx.x * chunk;
    int end = min(E, start + chunk);
    for (int e = start + tid; e < end; e += 256) {
        float a = ea[e];
        float s = b2s;
#pragma unroll
        for (int j = 0; j < 16; ++j) {
            float h = fmaxf(a * w1[j] + b1[j], 0.0f);
            s += h * w2[j];
        }
        float w = 1.0f / (1.0f + expf(-s));
        int d = dstv[e];
        int b = d >> 8;
        int p = gb[b] + atomicAdd(&lc[b], 1);
        unsigned payload = ((unsigned)(d & 255) << 16) |
                           (unsigned)__half_as_ushort(__float2half(w));
        spk[p] = make_int2(srcv[e], (int)payload);
    }
}

// -------- build pass 3: per-bucket grouping -> exact CSR + deg/dinv fused
// bucket's spk region cached in LDS when it fits (GCAP)
__global__ __launch_bounds__(256) void k_group(const int2* __restrict__ spk,
                                               const int* __restrict__ bbase,
                                               int2* __restrict__ slots,
                                               int* __restrict__ rowst,
                                               int* __restrict__ cntg,
                                               float* __restrict__ dinv,
                                               int nb, int n, int E) {
    __shared__ int cnt[256], sc[256], ls[256], cur[256];
    __shared__ float dsum[256];
    __shared__ int2 cache[GCAP];
    int b = blockIdx.x;
    int tid = threadIdx.x;
    int r0 = bbase[b];
    int r1 = (b + 1 < nb) ? bbase[b + 1] : E;
    int m = r1 - r0;
    bool lds = (m <= GCAP);
    cnt[tid] = 0; cur[tid] = 0; dsum[tid] = 0.0f;
    if (lds)
        for (int i = tid; i < m; i += 256) cache[i] = spk[r0 + i];
    __syncthreads();
    for (int i = tid; i < m; i += 256) {
        int2 pr = lds ? cache[i] : spk[r0 + i];
        int dl = (pr.y >> 16) & 255;
        atomicAdd(&cnt[dl], 1);
        atomicAdd(&dsum[dl], __half2float(__ushort_as_half((ushort)(pr.y & 0xffff))));
    }
    __syncthreads();
    sc[tid] = cnt[tid];
    __syncthreads();
    for (int o = 1; o < 256; o <<= 1) {
        int v = (tid >= o) ? sc[tid - o] : 0;
        __syncthreads();
        sc[tid] += v;
        __syncthreads();
    }
    ls[tid] = sc[tid] - cnt[tid];
    int dst = (b << 8) + tid;
    if (dst < n) {
        rowst[dst] = r0 + ls[tid];
        cntg[dst] = cnt[tid];
        dinv[dst] = 1.0f / sqrtf(1.0f + dsum[tid]);  // self-loop weight 1
    }
    __syncthreads();
    for (int i = tid; i < m; i += 256) {
        int2 pr = lds ? cache[i] : spk[r0 + i];
        int dl = (pr.y >> 16) & 255;
        float wf = __half2float(__ushort_as_half((ushort)(pr.y & 0xffff)));
        int p = r0 + ls[dl] + atomicAdd(&cur[dl], 1);
        slots[p] = make_int2(pr.x, __float_as_int(wf));
    }
}

// ------------- FUSED conv: aggregation (8 lanes/node, us8 gathers) + GEMM
// agg: t[i][:] = dinv[i]*( dinv[i]*H[i][:] + sum_e dinv[c]*ew*H[c][:] )
// out: Y[i][:] = relu?( t[i][:] @ W + bias )   (bf16 or fp32 out)
template <int OUTC, bool RELU, bool BF16OUT>
__global__ __launch_bounds__(512) void k_agg_gemm(const ushort* __restrict__ Hb,
                                                  const int2* __restrict__ slots,
                                                  const int* __restrict__ cnt,
                                                  const int* __restrict__ rowst,
                                                  const float* __restrict__ dinv,
                                                  const float* __restrict__ W,
                                                  const float* __restrict__ bias,
                                                  void* __restrict__ Yv, int n) {
    __shared__ __align__(16) float xs[64][68];     // agg results (pad 68)
    __shared__ __align__(16) float ws_[64 * OUTC];
    const us8* H8 = (const us8*)Hb;
    int tid = threadIdx.x;
    for (int i = tid; i < 64 * OUTC / 4; i += 512)
        ((float4*)ws_)[i] = ((const float4*)W)[i];

    int lane = tid & 63;
    int g = lane >> 3;          // node group within wave (8 lanes each)
    int s = lane & 7;           // sub-lane: features [s*8, s*8+8)
    int gbase = lane & 56;      // group base lane for shfl
    int nl = (tid >> 6) * 8 + g;  // node-local 0..63
    int node = blockIdx.x * 64 + nl;
    bool valid = node < n;
    int nc = valid ? node : 0;
    float di = dinv[nc];
    int c = valid ? cnt[nc] : 0;
    size_t base = (size_t)rowst[nc];

    float acc[8];
    us8 h0 = H8[(size_t)nc * 8 + s];
#pragma unroll
    for (int j = 0; j < 8; ++j) acc[j] = di * bf2f(h0[j]);

    // software-pipelined slots load: pr holds iteration bb, prefetch bb+8
    int2 pr = make_int2(0, 0);
    if (s < c) pr = slots[base + s];
    for (int bb = 0; bb < c; bb += 8) {
        int myc = 0;
        float myw = 0.0f;
        if (bb + s < c) {
            myc = pr.x;
            myw = __int_as_float(pr.y) * dinv[myc];
        }
        if (bb + 8 + s < c) pr = slots[base + bb + 8 + s];   // prefetch next
#pragma unroll
        for (int i = 0; i < 8; ++i) {       // zero-weight pads are free adds
            int ni = __shfl(myc, gbase + i);
            float wi = __shfl(myw, gbase + i);
            us8 v = H8[(size_t)ni * 8 + s];
#pragma unroll
            for (int j = 0; j < 8; ++j) acc[j] += wi * bf2f(v[j]);
        }
    }
#pragma unroll
    for (int j = 0; j < 8; ++j) xs[nl][s * 8 + j] = di * acc[j];
    __syncthreads();

    // ---- GEMM phase: Y[64,OUTC] = xs @ ws_  (xs rows broadcast from LDS)
    int col = tid % OUTC;
    constexpr int RSLOTS = 512 / OUTC;
    constexpr int RPT = 64 / RSLOTS;
    int rs = tid / OUTC;
    float wc[64];
#pragma unroll
    for (int k = 0; k < 64; ++k) wc[k] = ws_[k * OUTC + col];
    float bcol = bias[col];

    for (int rr = 0; rr < RPT; ++rr) {
        int r = rs * RPT + rr;
        const float4* x4 = (const float4*)&xs[r][0];
        float a = 0.0f;
#pragma unroll
        for (int k4 = 0; k4 < 16; ++k4) {
            float4 v = x4[k4];
            a += v.x * wc[4 * k4 + 0];
            a += v.y * wc[4 * k4 + 1];
            a += v.z * wc[4 * k4 + 2];
            a += v.w * wc[4 * k4 + 3];
        }
        float o = a + bcol;
        if (RELU) o = fmaxf(o, 0.0f);
        int gr = blockIdx.x * 64 + r;
        if (gr < n) {
            if (BF16OUT) ((ushort*)Yv)[(size_t)gr * OUTC + col] = f2bf(o);
            else         ((float*)Yv)[(size_t)gr * OUTC + col] = o;
        }
    }
}

// ------------------------------------- fold W2c@Wo, b2c@Wo+bo (tiny, 1 block)
__global__ __launch_bounds__(256) void k_prepW(const float* __restrict__ W2c,
                                               const float* __restrict__ Wo,
                                               const float* __restrict__ b2c,
                                               const float* __restrict__ bo,
                                               float* __restrict__ W2o,
                                               float* __restrict__ bo2) {
    int t = threadIdx.x;
    for (int idx = t; idx < 64 * 32; idx += 256) {
        int i = idx >> 5, j = idx & 31;
        float s = 0.0f;
        for (int k = 0; k < 64; ++k) s += W2c[i * 64 + k] * Wo[k * 32 + j];
        W2o[idx] = s;
    }
    if (t < 32) {
        float s = bo[t];
        for (int k = 0; k < 64; ++k) s += b2c[k] * Wo[k * 32 + t];
        bo2[t] = s;
    }
}

// ------------------------------------------- FALLBACK: edge MLP + count only
__global__ __launch_bounds__(256) void k_edge2(const float* __restrict__ ea,
                                               const float* __restrict__ Wd1,
                                               const float* __restrict__ bd1,
                                               const float* __restrict__ Wd2,
                                               const float* __restrict__ bd2,
                                               const int* __restrict__ dstv,
                                               float* __restrict__ ew,
                                               int* __restrict__ cnt, int E) {
    __shared__ float w1[16], b1[16], w2[16];
    __shared__ float b2s;
    if (threadIdx.x < 16) {
        w1[threadIdx.x] = Wd1[threadIdx.x];
        b1[threadIdx.x] = bd1[threadIdx.x];
        w2[threadIdx.x] = Wd2[threadIdx.x];
    }
    if (threadIdx.x == 0) b2s = bd2[0];
    __syncthreads();
    int e = blockIdx.x * 256 + threadIdx.x;
    if (e >= E) return;
    float a = ea[e];
    float s = b2s;
#pragma unroll
    for (int j = 0; j < 16; ++j) {
        float h = fmaxf(a * w1[j] + b1[j], 0.0f);
        s += h * w2[j];
    }
    float w = 1.0f / (1.0f + expf(-s));
    ew[e] = w;
    atomicAdd(&cnt[dstv[e]], 1);
}

// ------------------------------- FALLBACK: CSR row allocation (wave-scanned)
__global__ __launch_bounds__(256) void k_scan(const int* __restrict__ cnt,
                                              int* __restrict__ rowst,
                                              int* __restrict__ cursor,
                                              int* __restrict__ gcnt, int n) {
    int i = blockIdx.x * 256 + threadIdx.x;
    int lane = threadIdx.x & 63;
    int c = (i < n) ? cnt[i] : 0;
    int pref = c;
#pragma unroll
    for (int o = 1; o < 64; o <<= 1) {
        int t = __shfl_up(pref, o);
        if (lane >= o) pref += t;
    }
    int total = __shfl(pref, 63);
    int base = 0;
    if (lane == 63 && total > 0) base = atomicAdd(gcnt, total);
    base = __shfl(base, 63);
    if (i < n) {
        int start = base + pref - c;
        rowst[i] = start;
        cursor[i] = start;
    }
}

// ---------------------------------------------------- FALLBACK: CSR fill
__global__ __launch_bounds__(256) void k_fill2(const int* __restrict__ srcv,
                                               const int* __restrict__ dstv,
                                               const float* __restrict__ ew,
                                               int* __restrict__ cursor,
                                               int2* __restrict__ slots, int E) {
    int e = blockIdx.x * 256 + threadIdx.x;
    if (e >= E) return;
    int p = atomicAdd(&cursor[dstv[e]], 1);
    slots[p] = make_int2(srcv[e], __float_as_int(ew[e]));
}

// ------------------------------------------ FALLBACK: degree sum + dinv
__global__ __launch_bounds__(256) void k_deg(const int2* __restrict__ slots,
                                             const int* __restrict__ cnt,
                                             const int* __restrict__ rowst,
                                             float* __restrict__ dinv, int n) {
    int t = blockIdx.x * 256 + threadIdx.x;
    int g = t >> 3;
    int sub = t & 7;
    if (g >= n) return;
    int c = cnt[g];
    size_t base = (size_t)rowst[g];
    float s = 0.0f;
    for (int j = sub; j < c; j += 8) s += __int_as_float(slots[base + j].y);
    s += __shfl_xor(s, 1);
    s += __shfl_xor(s, 2);
    s += __shfl_xor(s, 4);
    if (sub == 0) dinv[g] = 1.0f / sqrtf(1.0f + s);
}

// ------------------------------------------------------------------- launch
extern "C" void kernel_launch(void* const* d_in, const int* in_sizes, int n_in,
                              void* d_out, int out_size, void* d_ws, size_t ws_size,
                              hipStream_t stream) {
    const float* x   = (const float*)d_in[0];
    const int*   ei  = (const int*)d_in[1];
    const float* ea  = (const float*)d_in[2];
    const float* Wd1 = (const float*)d_in[3];
    const float* bd1 = (const float*)d_in[4];
    const float* Wd2 = (const float*)d_in[5];
    const float* bd2 = (const float*)d_in[6];
    const float* W1c = (const float*)d_in[7];
    const float* b1c = (const float*)d_in[8];
    const float* W2c = (const float*)d_in[9];
    const float* b2c = (const float*)d_in[10];
    const float* Wo  = (const float*)d_in[11];
    const float* bo  = (const float*)d_in[12];

    const int N = in_sizes[0] / 64;
    const int E = in_sizes[2];
    const int* srcv = ei;
    const int* dstv = ei + E;
    const int NB = (N + 255) >> 8;

    size_t off = 0;
    auto alloc = [&](size_t bytes) -> void* {
        void* p = (char*)d_ws + off;
        off += (bytes + 255) & ~(size_t)255;
        return p;
    };

    // common
    int*    cntg  = (int*)   alloc((size_t)N * 4);
    int*    rowst = (int*)   alloc((size_t)N * 4);
    float*  dinv  = (float*) alloc((size_t)N * 4);
    ushort* xb    = (ushort*)alloc((size_t)N * 64 * 2);
    ushort* h1b   = (ushort*)alloc((size_t)N * 64 * 2);
    float*  W2o   = (float*) alloc(64 * 32 * 4);
    float*  bo2   = (float*) alloc(32 * 4);
    int2*   slots = (int2*)  alloc((size_t)E * 8);

    const int BF = (N + 63) / 64;      // fused conv blocks (64 nodes each)
    const int BT = (N * 16 + 255) / 256;
    const int GB = GBUILD;
    const int CHUNK = (E + GB - 1) / GB;

    size_t base_need = off;
    size_t sort_need = base_need + (((size_t)E * 8 + 255) & ~(size_t)255)
                       + 2 * ((size_t)GB * NBMAX * 4 + 256) + 16384;
    const bool fast = ws_size >= sort_need;

    if (fast) {
        int2* spk  = (int2*)alloc((size_t)E * 8);
        int* bh    = (int*) alloc((size_t)GB * NBMAX * 4);
        int* boff  = (int*) alloc((size_t)GB * NBMAX * 4);
        int* btot  = (int*) alloc(NBMAX * 4);
        int* bbase = (int*) alloc(NBMAX * 4);

        k_tobf16<<<BT, 256, 0, stream>>>((const float4*)x, (ushort4*)xb, N * 16);
        k_hist<<<GB, 256, 0, stream>>>(dstv, bh, E, CHUNK);
        k_scanA<<<NBMAX, 256, 0, stream>>>(bh, boff, btot);
        k_scanB<<<1, 512, 0, stream>>>(btot, bbase, NB);
        k_edge_scatter<<<GB, 256, 0, stream>>>(ea, Wd1, bd1, Wd2, bd2, srcv, dstv,
                                               bbase, boff, spk, E, CHUNK);
        k_group<<<NB, 256, 0, stream>>>(spk, bbase, slots, rowst, cntg, dinv,
                                        NB, N, E);
        k_prepW<<<1, 256, 0, stream>>>(W2c, Wo, b2c, bo, W2o, bo2);
        // conv1: agg(xb)+GEMM(W1c)+relu -> bf16 h1b
        k_agg_gemm<64, true, true><<<BF, 512, 0, stream>>>(
            xb, slots, cntg, rowst, dinv, W1c, b1c, h1b, N);
        // conv2+head folded: agg(h1b)+GEMM(W2o) -> fp32 d_out
        k_agg_gemm<32, false, false><<<BF, 512, 0, stream>>>(
            h1b, slots, cntg, rowst, dinv, W2o, bo2, d_out, N);
    } else {
        float* ew   = (float*)alloc((size_t)E * 4);
        int* cursor = (int*)  alloc((size_t)N * 4);
        int* gcnt   = (int*)  alloc(256);
        const int BN = (N + 255) / 256;
        const int BE = (E + 255) / 256;
        const int BD = (N * 8 + 255) / 256;
        hipMemsetAsync(cntg, 0, (size_t)N * 4, stream);
        hipMemsetAsync(gcnt, 0, 4, stream);
        k_tobf16<<<BT, 256, 0, stream>>>((const float4*)x, (ushort4*)xb, N * 16);
        k_edge2<<<BE, 256, 0, stream>>>(ea, Wd1, bd1, Wd2, bd2, dstv, ew, cntg, E);
        k_scan<<<BN, 256, 0, stream>>>(cntg, rowst, cursor, gcnt, N);
        k_fill2<<<BE, 256, 0, stream>>>(srcv, dstv, ew, cursor, slots, E);
        k_deg<<<BD, 256, 0, stream>>>(slots, cntg, rowst, dinv, N);
        k_prepW<<<1, 256, 0, stream>>>(W2c, Wo, b2c, bo, W2o, bo2);
        k_agg_gemm<64, true, true><<<BF, 512, 0, stream>>>(
            xb, slots, cntg, rowst, dinv, W1c, b1c, h1b, N);
        k_agg_gemm<32, false, false><<<BF, 512, 0, stream>>>(
            h1b, slots, cntg, rowst, dinv, W2o, bo2, d_out, N);
    }
}

// Round 12
// 269.904 us; speedup vs baseline: 1.1006x; 1.1006x over previous
//
#include <hip/hip_runtime.h>
#include <hip/hip_fp16.h>
#include <math.h>

#define NBMAX 400   // max dst buckets (dst>>8), N=100k -> 391
#define GBUILD 512  // build grid (k_scanA assumes it; 512 keeps scatter runs ~64B)

typedef __attribute__((ext_vector_type(8))) ushort us8;

__device__ inline ushort f2bf(float f) {
    unsigned u = __float_as_uint(f);
    u += 0x7fff + ((u >> 16) & 1);   // RNE
    return (ushort)(u >> 16);
}
__device__ inline float bf2f(ushort u) {
    return __uint_as_float(((unsigned)u) << 16);
}

// ----------------------------------------------------------- fp32 -> bf16
__global__ __launch_bounds__(256) void k_tobf16(const float4* __restrict__ X4,
                                                ushort4* __restrict__ Y4, int n4) {
    int i = blockIdx.x * 256 + threadIdx.x;
    if (i >= n4) return;
    float4 v = X4[i];
    ushort4 o;
    o.x = f2bf(v.x); o.y = f2bf(v.y); o.z = f2bf(v.z); o.w = f2bf(v.w);
    Y4[i] = o;
}

// ------------- build pass 0: per-block bucket histogram -> bh[blk][bucket]
__global__ __launch_bounds__(256) void k_hist(const int* __restrict__ dstv,
                                              int* __restrict__ bh,
                                              int E, int chunk) {
    __shared__ int lh[NBMAX];
    int tid = threadIdx.x;
    for (int i = tid; i < NBMAX; i += 256) lh[i] = 0;
    __syncthreads();
    int start = blockIdx.x * chunk;
    int end = min(E, start + chunk);
    for (int e = start + tid; e < end; e += 256)
        atomicAdd(&lh[dstv[e] >> 8], 1);
    __syncthreads();
    int* row = bh + (size_t)blockIdx.x * NBMAX;
    for (int i = tid; i < NBMAX; i += 256) row[i] = lh[i];
}

// ------------- build pass 1a: per-bucket scan over blocks -> boff, btot
__global__ __launch_bounds__(256) void k_scanA(const int* __restrict__ bh,
                                               int* __restrict__ boff,
                                               int* __restrict__ btot) {
    __shared__ int s[GBUILD];
    int b = blockIdx.x;     // bucket
    int t = threadIdx.x;
    int i0 = t, i1 = t + 256;
    s[i0] = bh[(size_t)i0 * NBMAX + b];
    s[i1] = bh[(size_t)i1 * NBMAX + b];
    __syncthreads();
    int c0 = s[i0], c1 = s[i1];
    for (int o = 1; o < GBUILD; o <<= 1) {
        int v0 = (i0 >= o) ? s[i0 - o] : 0;
        int v1 = (i1 >= o) ? s[i1 - o] : 0;
        __syncthreads();
        s[i0] += v0;
        s[i1] += v1;
        __syncthreads();
    }
    boff[(size_t)i0 * NBMAX + b] = s[i0] - c0;   // exclusive
    boff[(size_t)i1 * NBMAX + b] = s[i1] - c1;
    if (t == 0) btot[b] = s[GBUILD - 1];
}

// ------------- build pass 1b: scan bucket totals -> bbase (1 block)
__global__ __launch_bounds__(512) void k_scanB(const int* __restrict__ btot,
                                               int* __restrict__ bbase, int nb) {
    __shared__ int s[512];
    int t = threadIdx.x;
    int c = (t < nb) ? btot[t] : 0;
    s[t] = c;
    __syncthreads();
    for (int o = 1; o < 512; o <<= 1) {
        int v = (t >= o) ? s[t - o] : 0;
        __syncthreads();
        s[t] += v;
        __syncthreads();
    }
    if (t < nb) bbase[t] = s[t] - c;
}

// ------- build pass 2: SINGLE-PASS edge MLP + packed 8B bucket scatter
// spk[p] = { src, (dst&255)<<16 | fp16(w) }
__global__ __launch_bounds__(256) void k_edge_scatter(const float* __restrict__ ea,
                                                      const float* __restrict__ Wd1,
                                                      const float* __restrict__ bd1,
                                                      const float* __restrict__ Wd2,
                                                      const float* __restrict__ bd2,
                                                      const int* __restrict__ srcv,
                                                      const int* __restrict__ dstv,
                                                      const int* __restrict__ bbase,
                                                      const int* __restrict__ boff,
                                                      int2* __restrict__ spk,
                                                      int E, int chunk) {
    __shared__ float w1[16], b1[16], w2[16];
    __shared__ float b2s;
    __shared__ int gb[NBMAX], lc[NBMAX];
    int tid = threadIdx.x;
    if (tid < 16) {
        w1[tid] = Wd1[tid];
        b1[tid] = bd1[tid];
        w2[tid] = Wd2[tid];
    }
    if (tid == 0) b2s = bd2[0];
    const int* brow = boff + (size_t)blockIdx.x * NBMAX;
    for (int i = tid; i < NBMAX; i += 256) {
        gb[i] = bbase[i] + brow[i];
        lc[i] = 0;
    }
    __syncthreads();
    int start = blockIdx.x * chunk;
    int end = min(E, start + chunk);
    for (int e = start + tid; e < end; e += 256) {
        float a = ea[e];
        float s = b2s;
#pragma unroll
        for (int j = 0; j < 16; ++j) {
            float h = fmaxf(a * w1[j] + b1[j], 0.0f);
            s += h * w2[j];
        }
        float w = 1.0f / (1.0f + expf(-s));
        int d = dstv[e];
        int b = d >> 8;
        int p = gb[b] + atomicAdd(&lc[b], 1);
        unsigned payload = ((unsigned)(d & 255) << 16) |
                           (unsigned)__half_as_ushort(__float2half(w));
        spk[p] = make_int2(srcv[e], (int)payload);
    }
}

// -------- build pass 3: per-bucket grouping -> exact CSR + deg/dinv fused
__global__ __launch_bounds__(256) void k_group(const int2* __restrict__ spk,
                                               const int* __restrict__ bbase,
                                               int2* __restrict__ slots,
                                               int* __restrict__ rowst,
                                               int* __restrict__ cntg,
                                               float* __restrict__ dinv,
                                               int nb, int n, int E) {
    __shared__ int cnt[256], sc[256], ls[256], cur[256];
    __shared__ float dsum[256];
    int b = blockIdx.x;
    int tid = threadIdx.x;
    int r0 = bbase[b];
    int r1 = (b + 1 < nb) ? bbase[b + 1] : E;
    cnt[tid] = 0; cur[tid] = 0; dsum[tid] = 0.0f;
    __syncthreads();
    for (int i = r0 + tid; i < r1; i += 256) {
        int2 pr = spk[i];
        int dl = (pr.y >> 16) & 255;
        atomicAdd(&cnt[dl], 1);
        atomicAdd(&dsum[dl], __half2float(__ushort_as_half((ushort)(pr.y & 0xffff))));
    }
    __syncthreads();
    sc[tid] = cnt[tid];
    __syncthreads();
    for (int o = 1; o < 256; o <<= 1) {
        int v = (tid >= o) ? sc[tid - o] : 0;
        __syncthreads();
        sc[tid] += v;
        __syncthreads();
    }
    ls[tid] = sc[tid] - cnt[tid];
    int dst = (b << 8) + tid;
    if (dst < n) {
        rowst[dst] = r0 + ls[tid];
        cntg[dst] = cnt[tid];
        dinv[dst] = 1.0f / sqrtf(1.0f + dsum[tid]);  // self-loop weight 1
    }
    __syncthreads();
    for (int i = r0 + tid; i < r1; i += 256) {
        int2 pr = spk[i];
        int dl = (pr.y >> 16) & 255;
        float wf = __half2float(__ushort_as_half((ushort)(pr.y & 0xffff)));
        int p = r0 + ls[dl] + atomicAdd(&cur[dl], 1);
        slots[p] = make_int2(pr.x, __float_as_int(wf));
    }
}

// ------------- FUSED conv: aggregation (8 lanes/node, us8 gathers) + GEMM
// 256 threads / 32 nodes per block -> 6-8 blocks/CU (was 4 at 512 thr)
template <int OUTC, bool RELU, bool BF16OUT>
__global__ __launch_bounds__(256) void k_agg_gemm(const ushort* __restrict__ Hb,
                                                  const int2* __restrict__ slots,
                                                  const int* __restrict__ cnt,
                                                  const int* __restrict__ rowst,
                                                  const float* __restrict__ dinv,
                                                  const float* __restrict__ W,
                                                  const float* __restrict__ bias,
                                                  void* __restrict__ Yv, int n) {
    __shared__ __align__(16) float xs[32][68];     // agg results (pad 68)
    __shared__ __align__(16) float ws_[64 * OUTC];
    const us8* H8 = (const us8*)Hb;
    int tid = threadIdx.x;
    for (int i = tid; i < 64 * OUTC / 4; i += 256)
        ((float4*)ws_)[i] = ((const float4*)W)[i];

    int lane = tid & 63;
    int g = lane >> 3;          // node group within wave (8 lanes each)
    int s = lane & 7;           // sub-lane: features [s*8, s*8+8)
    int gbase = lane & 56;      // group base lane for shfl
    int nl = (tid >> 6) * 8 + g;  // node-local 0..31
    int node = blockIdx.x * 32 + nl;
    bool valid = node < n;
    int nc = valid ? node : 0;
    float di = dinv[nc];
    int c = valid ? cnt[nc] : 0;
    size_t base = (size_t)rowst[nc];

    float acc[8];
    us8 h0 = H8[(size_t)nc * 8 + s];
#pragma unroll
    for (int j = 0; j < 8; ++j) acc[j] = di * bf2f(h0[j]);

    // software-pipelined slots load: pr holds iteration bb, prefetch bb+8
    int2 pr = make_int2(0, 0);
    if (s < c) pr = slots[base + s];
    for (int bb = 0; bb < c; bb += 8) {
        int myc = 0;
        float myw = 0.0f;
        if (bb + s < c) {
            myc = pr.x;
            myw = __int_as_float(pr.y) * dinv[myc];
        }
        if (bb + 8 + s < c) pr = slots[base + bb + 8 + s];   // prefetch next
#pragma unroll
        for (int i = 0; i < 8; ++i) {       // zero-weight pads are free adds
            int ni = __shfl(myc, gbase + i);
            float wi = __shfl(myw, gbase + i);
            us8 v = H8[(size_t)ni * 8 + s];
#pragma unroll
            for (int j = 0; j < 8; ++j) acc[j] += wi * bf2f(v[j]);
        }
    }
#pragma unroll
    for (int j = 0; j < 8; ++j) xs[nl][s * 8 + j] = di * acc[j];
    __syncthreads();

    // ---- GEMM phase: Y[32,OUTC] = xs @ ws_  (xs rows broadcast from LDS)
    int col = tid % OUTC;
    constexpr int RSLOTS = 256 / OUTC;
    constexpr int RPT = 32 / RSLOTS;
    int rs = tid / OUTC;
    float wc[64];
#pragma unroll
    for (int k = 0; k < 64; ++k) wc[k] = ws_[k * OUTC + col];
    float bcol = bias[col];

    for (int rr = 0; rr < RPT; ++rr) {
        int r = rs * RPT + rr;
        const float4* x4 = (const float4*)&xs[r][0];
        float a = 0.0f;
#pragma unroll
        for (int k4 = 0; k4 < 16; ++k4) {
            float4 v = x4[k4];
            a += v.x * wc[4 * k4 + 0];
            a += v.y * wc[4 * k4 + 1];
            a += v.z * wc[4 * k4 + 2];
            a += v.w * wc[4 * k4 + 3];
        }
        float o = a + bcol;
        if (RELU) o = fmaxf(o, 0.0f);
        int gr = blockIdx.x * 32 + r;
        if (gr < n) {
            if (BF16OUT) ((ushort*)Yv)[(size_t)gr * OUTC + col] = f2bf(o);
            else         ((float*)Yv)[(size_t)gr * OUTC + col] = o;
        }
    }
}

// ------------------------------------- fold W2c@Wo, b2c@Wo+bo (tiny, 1 block)
__global__ __launch_bounds__(256) void k_prepW(const float* __restrict__ W2c,
                                               const float* __restrict__ Wo,
                                               const float* __restrict__ b2c,
                                               const float* __restrict__ bo,
                                               float* __restrict__ W2o,
                                               float* __restrict__ bo2) {
    int t = threadIdx.x;
    for (int idx = t; idx < 64 * 32; idx += 256) {
        int i = idx >> 5, j = idx & 31;
        float s = 0.0f;
        for (int k = 0; k < 64; ++k) s += W2c[i * 64 + k] * Wo[k * 32 + j];
        W2o[idx] = s;
    }
    if (t < 32) {
        float s = bo[t];
        for (int k = 0; k < 64; ++k) s += b2c[k] * Wo[k * 32 + t];
        bo2[t] = s;
    }
}

// ------------------------------------------- FALLBACK: edge MLP + count only
__global__ __launch_bounds__(256) void k_edge2(const float* __restrict__ ea,
                                               const float* __restrict__ Wd1,
                                               const float* __restrict__ bd1,
                                               const float* __restrict__ Wd2,
                                               const float* __restrict__ bd2,
                                               const int* __restrict__ dstv,
                                               float* __restrict__ ew,
                                               int* __restrict__ cnt, int E) {
    __shared__ float w1[16], b1[16], w2[16];
    __shared__ float b2s;
    if (threadIdx.x < 16) {
        w1[threadIdx.x] = Wd1[threadIdx.x];
        b1[threadIdx.x] = bd1[threadIdx.x];
        w2[threadIdx.x] = Wd2[threadIdx.x];
    }
    if (threadIdx.x == 0) b2s = bd2[0];
    __syncthreads();
    int e = blockIdx.x * 256 + threadIdx.x;
    if (e >= E) return;
    float a = ea[e];
    float s = b2s;
#pragma unroll
    for (int j = 0; j < 16; ++j) {
        float h = fmaxf(a * w1[j] + b1[j], 0.0f);
        s += h * w2[j];
    }
    float w = 1.0f / (1.0f + expf(-s));
    ew[e] = w;
    atomicAdd(&cnt[dstv[e]], 1);
}

// ------------------------------- FALLBACK: CSR row allocation (wave-scanned)
__global__ __launch_bounds__(256) void k_scan(const int* __restrict__ cnt,
                                              int* __restrict__ rowst,
                                              int* __restrict__ cursor,
                                              int* __restrict__ gcnt, int n) {
    int i = blockIdx.x * 256 + threadIdx.x;
    int lane = threadIdx.x & 63;
    int c = (i < n) ? cnt[i] : 0;
    int pref = c;
#pragma unroll
    for (int o = 1; o < 64; o <<= 1) {
        int t = __shfl_up(pref, o);
        if (lane >= o) pref += t;
    }
    int total = __shfl(pref, 63);
    int base = 0;
    if (lane == 63 && total > 0) base = atomicAdd(gcnt, total);
    base = __shfl(base, 63);
    if (i < n) {
        int start = base + pref - c;
        rowst[i] = start;
        cursor[i] = start;
    }
}

// ---------------------------------------------------- FALLBACK: CSR fill
__global__ __launch_bounds__(256) void k_fill2(const int* __restrict__ srcv,
                                               const int* __restrict__ dstv,
                                               const float* __restrict__ ew,
                                               int* __restrict__ cursor,
                                               int2* __restrict__ slots, int E) {
    int e = blockIdx.x * 256 + threadIdx.x;
    if (e >= E) return;
    int p = atomicAdd(&cursor[dstv[e]], 1);
    slots[p] = make_int2(srcv[e], __float_as_int(ew[e]));
}

// ------------------------------------------ FALLBACK: degree sum + dinv
__global__ __launch_bounds__(256) void k_deg(const int2* __restrict__ slots,
                                             const int* __restrict__ cnt,
                                             const int* __restrict__ rowst,
                                             float* __restrict__ dinv, int n) {
    int t = blockIdx.x * 256 + threadIdx.x;
    int g = t >> 3;
    int sub = t & 7;
    if (g >= n) return;
    int c = cnt[g];
    size_t base = (size_t)rowst[g];
    float s = 0.0f;
    for (int j = sub; j < c; j += 8) s += __int_as_float(slots[base + j].y);
    s += __shfl_xor(s, 1);
    s += __shfl_xor(s, 2);
    s += __shfl_xor(s, 4);
    if (sub == 0) dinv[g] = 1.0f / sqrtf(1.0f + s);
}

// ------------------------------------------------------------------- launch
extern "C" void kernel_launch(void* const* d_in, const int* in_sizes, int n_in,
                              void* d_out, int out_size, void* d_ws, size_t ws_size,
                              hipStream_t stream) {
    const float* x   = (const float*)d_in[0];
    const int*   ei  = (const int*)d_in[1];
    const float* ea  = (const float*)d_in[2];
    const float* Wd1 = (const float*)d_in[3];
    const float* bd1 = (const float*)d_in[4];
    const float* Wd2 = (const float*)d_in[5];
    const float* bd2 = (const float*)d_in[6];
    const float* W1c = (const float*)d_in[7];
    const float* b1c = (const float*)d_in[8];
    const float* W2c = (const float*)d_in[9];
    const float* b2c = (const float*)d_in[10];
    const float* Wo  = (const float*)d_in[11];
    const float* bo  = (const float*)d_in[12];

    const int N = in_sizes[0] / 64;
    const int E = in_sizes[2];
    const int* srcv = ei;
    const int* dstv = ei + E;
    const int NB = (N + 255) >> 8;

    size_t off = 0;
    auto alloc = [&](size_t bytes) -> void* {
        void* p = (char*)d_ws + off;
        off += (bytes + 255) & ~(size_t)255;
        return p;
    };

    // common
    int*    cntg  = (int*)   alloc((size_t)N * 4);
    int*    rowst = (int*)   alloc((size_t)N * 4);
    float*  dinv  = (float*) alloc((size_t)N * 4);
    ushort* xb    = (ushort*)alloc((size_t)N * 64 * 2);
    ushort* h1b   = (ushort*)alloc((size_t)N * 64 * 2);
    float*  W2o   = (float*) alloc(64 * 32 * 4);
    float*  bo2   = (float*) alloc(32 * 4);
    int2*   slots = (int2*)  alloc((size_t)E * 8);

    const int BF = (N + 31) / 32;      // fused conv blocks (32 nodes each)
    const int BT = (N * 16 + 255) / 256;
    const int GB = GBUILD;
    const int CHUNK = (E + GB - 1) / GB;

    size_t base_need = off;
    size_t sort_need = base_need + (((size_t)E * 8 + 255) & ~(size_t)255)
                       + 2 * ((size_t)GB * NBMAX * 4 + 256) + 16384;
    const bool fast = ws_size >= sort_need;

    if (fast) {
        int2* spk  = (int2*)alloc((size_t)E * 8);
        int* bh    = (int*) alloc((size_t)GB * NBMAX * 4);
        int* boff  = (int*) alloc((size_t)GB * NBMAX * 4);
        int* btot  = (int*) alloc(NBMAX * 4);
        int* bbase = (int*) alloc(NBMAX * 4);

        k_tobf16<<<BT, 256, 0, stream>>>((const float4*)x, (ushort4*)xb, N * 16);
        k_hist<<<GB, 256, 0, stream>>>(dstv, bh, E, CHUNK);
        k_scanA<<<NBMAX, 256, 0, stream>>>(bh, boff, btot);
        k_scanB<<<1, 512, 0, stream>>>(btot, bbase, NB);
        k_edge_scatter<<<GB, 256, 0, stream>>>(ea, Wd1, bd1, Wd2, bd2, srcv, dstv,
                                               bbase, boff, spk, E, CHUNK);
        k_group<<<NB, 256, 0, stream>>>(spk, bbase, slots, rowst, cntg, dinv,
                                        NB, N, E);
        k_prepW<<<1, 256, 0, stream>>>(W2c, Wo, b2c, bo, W2o, bo2);
        // conv1: agg(xb)+GEMM(W1c)+relu -> bf16 h1b
        k_agg_gemm<64, true, true><<<BF, 256, 0, stream>>>(
            xb, slots, cntg, rowst, dinv, W1c, b1c, h1b, N);
        // conv2+head folded: agg(h1b)+GEMM(W2o) -> fp32 d_out
        k_agg_gemm<32, false, false><<<BF, 256, 0, stream>>>(
            h1b, slots, cntg, rowst, dinv, W2o, bo2, d_out, N);
    } else {
        float* ew   = (float*)alloc((size_t)E * 4);
        int* cursor = (int*)  alloc((size_t)N * 4);
        int* gcnt   = (int*)  alloc(256);
        const int BN = (N + 255) / 256;
        const int BE = (E + 255) / 256;
        const int BD = (N * 8 + 255) / 256;
        hipMemsetAsync(cntg, 0, (size_t)N * 4, stream);
        hipMemsetAsync(gcnt, 0, 4, stream);
        k_tobf16<<<BT, 256, 0, stream>>>((const float4*)x, (ushort4*)xb, N * 16);
        k_edge2<<<BE, 256, 0, stream>>>(ea, Wd1, bd1, Wd2, bd2, dstv, ew, cntg, E);
        k_scan<<<BN, 256, 0, stream>>>(cntg, rowst, cursor, gcnt, N);
        k_fill2<<<BE, 256, 0, stream>>>(srcv, dstv, ew, cursor, slots, E);
        k_deg<<<BD, 256, 0, stream>>>(slots, cntg, rowst, dinv, N);
        k_prepW<<<1, 256, 0, stream>>>(W2c, Wo, b2c, bo, W2o, bo2);
        k_agg_gemm<64, true, true><<<BF, 256, 0, stream>>>(
            xb, slots, cntg, rowst, dinv, W1c, b1c, h1b, N);
        k_agg_gemm<32, false, false><<<BF, 256, 0, stream>>>(
            h1b, slots, cntg, rowst, dinv, W2o, bo2, d_out, N);
    }
}